// Round 1
// baseline (454.960 us; speedup 1.0000x reference)
//
#include <hip/hip_runtime.h>
#include <stdint.h>

#define NROWS 16384   // 16*32*32 spatial positions
#define NCODES 8192
#define DIM 256

typedef __attribute__((ext_vector_type(8))) short bf16x8;  // 8 bf16 = 4 VGPRs
typedef __attribute__((ext_vector_type(4))) float f32x4;

__device__ __forceinline__ unsigned short f2bf(float f) {
  union { float f; unsigned int u; } v; v.f = f;
  unsigned int u = v.u;
  return (unsigned short)((u + 0x7FFFu + ((u >> 16) & 1u)) >> 16);  // RNE
}

// async global->LDS, 16B per lane; LDS dest = wave-uniform base + lane*16
__device__ __forceinline__ void glds16(const void* g, void* l) {
  __builtin_amdgcn_global_load_lds(
      (const __attribute__((address_space(1))) unsigned int*)g,
      (__attribute__((address_space(3))) unsigned int*)l, 16, 0, 0);
}

// order-preserving float->u32, packed with index; u64-min == (dist, lowest idx)
__device__ __forceinline__ unsigned long long packdi(float d, int idx) {
  unsigned int u = __float_as_uint(d);
  u = (u & 0x80000000u) ? ~u : (u | 0x80000000u);
  return ((unsigned long long)u << 32) | (unsigned int)idx;
}
__device__ __forceinline__ float unpackf(unsigned long long k) {
  unsigned int u = (unsigned int)(k >> 32);
  u = (u & 0x80000000u) ? (u & 0x7FFFFFFFu) : ~u;
  return __uint_as_float(u);
}
__device__ __forceinline__ unsigned long long u64min(unsigned long long a,
                                                     unsigned long long b) {
  return a < b ? a : b;
}
__device__ __forceinline__ unsigned long long shflx64(unsigned long long v, int m) {
  int lo = __shfl_xor((int)(unsigned int)v, m);
  int hi = __shfl_xor((int)(v >> 32), m);
  return ((unsigned long long)(unsigned int)hi << 32) | (unsigned int)lo;
}

// ---- Phase 0a: NCHW -> (row, d) transpose; write fp32 + bf16 copies --------
__global__ __launch_bounds__(256) void prep_z(const float* __restrict__ z,
                                              float* __restrict__ flatz,
                                              ushort* __restrict__ zb) {
  __shared__ float t[32][33];  // +1 pad: no bank conflicts
  const int tx = threadIdx.x & 31, ty = threadIdx.x >> 5;  // 32 x 8
  const int b = blockIdx.z, ct = blockIdx.y, ht = blockIdx.x;
  const float* src = z + (size_t)b * 262144 + (size_t)(ct * 32) * 1024 + ht * 32;
#pragma unroll
  for (int i = 0; i < 4; ++i) {
    int c = ty + i * 8;
    t[c][tx] = src[c * 1024 + tx];  // coalesced in hw
  }
  __syncthreads();
#pragma unroll
  for (int i = 0; i < 4; ++i) {
    int hw = ty + i * 8;
    int row = b * 1024 + ht * 32 + hw;
    float v = t[tx][hw];
    flatz[(size_t)row * 256 + ct * 32 + tx] = v;  // coalesced in d
    zb[(size_t)row * 256 + ct * 32 + tx] = f2bf(v);
  }
}

// ---- Phase 0b: codebook -> bf16 + fp32 ||e||^2 -----------------------------
__global__ __launch_bounds__(256) void prep_cb(const float* __restrict__ cb,
                                               ushort* __restrict__ eb,
                                               float* __restrict__ enorm) {
  const int lane = threadIdx.x & 63, wave = threadIdx.x >> 6;
  const int code = blockIdx.x * 4 + wave;
  float4 v = *(const float4*)(cb + (size_t)code * 256 + lane * 4);
  ushort4 o;
  o.x = f2bf(v.x); o.y = f2bf(v.y); o.z = f2bf(v.z); o.w = f2bf(v.w);
  *(ushort4*)(eb + (size_t)code * 256 + lane * 4) = o;
  float ss = v.x * v.x + v.y * v.y + v.z * v.z + v.w * v.w;
#pragma unroll
  for (int s = 1; s < 64; s <<= 1) ss += __shfl_xor(ss, s);
  if (lane == 0) enorm[code] = ss;
}

// ---- Phase 1: bf16 MFMA distance GEMM + per-(row, 64-code-chunk) argmin ----
// A (MFMA M) = codebook tile, B (MFMA N) = z-row tile. 128x128 tile, BK=32,
// 4 waves each computing a 64x64 quadrant as 4x4 16x16x32 fragments.
// Epilogue stores bm[zrow][chunk64] = pack(min dist, idx) — one writer per
// entry (chunk == this wave's 64-code half), so plain stores, no atomics.
__global__ __launch_bounds__(256) void vq_gemm(const ushort* __restrict__ eb,
                                               const ushort* __restrict__ zb,
                                               const float* __restrict__ enorm,
                                               unsigned long long* __restrict__ bm) {
  __shared__ __align__(16) ushort As[128 * 32];  // codes x k, 8 KB
  __shared__ __align__(16) ushort Bs[128 * 32];  // zrows x k, 8 KB
  const int tid = threadIdx.x;
  const int wave = tid >> 6, lane = tid & 63;
  const int wr = wave >> 1, wc = wave & 1;  // code half / zrow half
  const int code0 = blockIdx.x * 128;
  const int zrow0 = blockIdx.y * 128;

  f32x4 acc[4][4] = {};  // [code frag i][zrow frag j]

  // staging map: LDS slot (l&3) of row (l>>2) holds global k-chunk
  // (l&3)^(row&3)  — XOR swizzle cuts ds_read_b128 conflicts 8-way -> 4-way
  const int r_in = lane >> 2;
  const int kc = (lane & 3) ^ (r_in & 3);
  ushort* As0 = As + wave * 512;        // each glds inst fills 16 rows (1 KB)
  ushort* As1 = As + (wave + 4) * 512;
  ushort* Bs0 = Bs + wave * 512;
  ushort* Bs1 = Bs + (wave + 4) * 512;
  const ushort* aG0 = eb + (size_t)(code0 + wave * 16 + r_in) * 256 + kc * 8;
  const ushort* aG1 = eb + (size_t)(code0 + 64 + wave * 16 + r_in) * 256 + kc * 8;
  const ushort* bG0 = zb + (size_t)(zrow0 + wave * 16 + r_in) * 256 + kc * 8;
  const ushort* bG1 = zb + (size_t)(zrow0 + 64 + wave * 16 + r_in) * 256 + kc * 8;

  const int q = lane >> 4;    // k-quad for A/B frags; row-quad for C/D
  const int l15 = lane & 15;
  const int slot = (q ^ (l15 & 3)) * 8;  // un-swizzle on read

  for (int k0 = 0; k0 < 8; ++k0) {
    glds16(aG0 + k0 * 32, As0);
    glds16(aG1 + k0 * 32, As1);
    glds16(bG0 + k0 * 32, Bs0);
    glds16(bG1 + k0 * 32, Bs1);
    __syncthreads();  // compiler drains vmcnt before s_barrier (m97 pattern)
    bf16x8 af[4], bf[4];
#pragma unroll
    for (int i = 0; i < 4; ++i)
      af[i] = *(const bf16x8*)(As + (wr * 64 + i * 16 + l15) * 32 + slot);
#pragma unroll
    for (int j = 0; j < 4; ++j)
      bf[j] = *(const bf16x8*)(Bs + (wc * 64 + j * 16 + l15) * 32 + slot);
#pragma unroll
    for (int i = 0; i < 4; ++i)
#pragma unroll
      for (int j = 0; j < 4; ++j)
        acc[i][j] = __builtin_amdgcn_mfma_f32_16x16x32_bf16(af[i], bf[j],
                                                            acc[i][j], 0, 0, 0);
    __syncthreads();  // protect LDS before next stage
  }

  // epilogue: dist = enorm - 2*dot ; C/D layout col=lane&15 (zrow), row=q*4+r (code)
  float en[4][4];
#pragma unroll
  for (int i = 0; i < 4; ++i) {
    float4 e = *(const float4*)(enorm + code0 + wr * 64 + i * 16 + q * 4);
    en[i][0] = e.x; en[i][1] = e.y; en[i][2] = e.z; en[i][3] = e.w;
  }
#pragma unroll
  for (int j = 0; j < 4; ++j) {
    float bd = 3.4e38f; int bi = 0;
#pragma unroll
    for (int i = 0; i < 4; ++i)
#pragma unroll
      for (int r = 0; r < 4; ++r) {
        float d = fmaf(-2.f, acc[i][j][r], en[i][r]);
        int c = code0 + wr * 64 + i * 16 + q * 4 + r;  // ascending: tie keeps lowest
        if (d < bd) { bd = d; bi = c; }
      }
    unsigned long long key = packdi(bd, bi);
    key = u64min(key, shflx64(key, 16));  // merge the 4 q-groups (same zrow set)
    key = u64min(key, shflx64(key, 32));
    if (lane < 16) {
      int zr = zrow0 + wc * 64 + j * 16 + lane;
      bm[(size_t)zr * 128 + blockIdx.x * 2 + wr] = key;
    }
  }
}

// ---- Phase 2: fp32 refinement + gather -------------------------------------
// One block per row. Scan 128 chunk minima; recompute every chunk whose approx
// min <= rowmin + 1.0 (>>38 sigma of bf16 error) exactly in fp32; lowest-index
// tie-break matches numpy argmin.
__global__ __launch_bounds__(256) void vq_select(
    const unsigned long long* __restrict__ bm, const float* __restrict__ flatz,
    const float* __restrict__ cb, const float* __restrict__ enorm,
    float* __restrict__ zq, float* __restrict__ oidx) {
  __shared__ unsigned long long sred[4];
  __shared__ unsigned long long cmask[4];
  __shared__ unsigned long long sfin;
  const int row = blockIdx.x;
  const int tid = threadIdx.x, lane = tid & 63, wave = tid >> 6;

  unsigned long long e = (tid < 128) ? bm[(size_t)row * 128 + tid] : ~0ull;
  unsigned long long m = e;
#pragma unroll
  for (int s = 1; s < 64; s <<= 1) m = u64min(m, shflx64(m, s));
  if (lane == 0) sred[wave] = m;
  __syncthreads();
  unsigned long long rowmin =
      u64min(u64min(sred[0], sred[1]), u64min(sred[2], sred[3]));
  float thr = unpackf(rowmin) + 1.0f;
  unsigned long long bal = __ballot(tid < 128 && unpackf(e) <= thr);
  if (lane == 0) cmask[wave] = bal;  // waves 2,3 contribute 0
  __syncthreads();

  float bd = 3.4e38f; int bi = -1;
  const float* zp = flatz + (size_t)row * 256 + (tid & 3) * 64;
  for (int half = 0; half < 2; ++half) {
    unsigned long long mask = cmask[half];
    while (mask) {
      int b = __ffsll(mask) - 1;
      mask &= mask - 1;
      int code = (half * 64 + b) * 64 + (tid >> 2);  // 4 threads per code
      const float* cp = cb + (size_t)code * 256 + (tid & 3) * 64;
      float s = 0.f;
#pragma unroll
      for (int d = 0; d < 64; d += 4) {
        float4 zv = *(const float4*)(zp + d);
        float4 cv = *(const float4*)(cp + d);
        s = fmaf(zv.x, cv.x, s); s = fmaf(zv.y, cv.y, s);
        s = fmaf(zv.z, cv.z, s); s = fmaf(zv.w, cv.w, s);
      }
      s += __shfl_xor(s, 1);
      s += __shfl_xor(s, 2);
      if ((tid & 3) == 0) {
        float d = fmaf(-2.f, s, enorm[code]);
        if (d < bd) { bd = d; bi = code; }  // ascending order: tie keeps lowest
      }
    }
  }
  unsigned long long key = (bi >= 0) ? packdi(bd, bi) : ~0ull;
#pragma unroll
  for (int s = 1; s < 64; s <<= 1) key = u64min(key, shflx64(key, s));
  if (lane == 0) sred[wave] = key;
  __syncthreads();
  if (tid == 0)
    sfin = u64min(u64min(sred[0], sred[1]), u64min(sred[2], sred[3]));
  __syncthreads();
  int idx = (int)(sfin & 0xFFFFFFFFull);
  if (tid == 0) oidx[row] = (float)idx;
  zq[(size_t)row * 256 + tid] = cb[(size_t)idx * 256 + tid];  // exact fp32 gather
}

// ---- launch ----------------------------------------------------------------
extern "C" void kernel_launch(void* const* d_in, const int* in_sizes, int n_in,
                              void* d_out, int out_size, void* d_ws, size_t ws_size,
                              hipStream_t stream) {
  const float* z = (const float*)d_in[0];   // (16,256,32,32) fp32
  const float* cb = (const float*)d_in[1];  // (8192,256) fp32
  char* ws = (char*)d_ws;
  // ws layout: zb 8M | eb 4M | enorm 32K | flatz 16M @13M | bm 16M @29M  (45 MB)
  ushort* zb = (ushort*)(ws);
  ushort* eb = (ushort*)(ws + (8u << 20));
  float* enorm = (float*)(ws + (12u << 20));
  float* flatz = (float*)(ws + (13u << 20));
  unsigned long long* bm = (unsigned long long*)(ws + (29u << 20));
  float* zq = (float*)d_out;                      // (16384,256) fp32
  float* oidx = zq + (size_t)NROWS * DIM;         // (16384,) as fp32 values

  prep_z<<<dim3(32, 8, 16), 256, 0, stream>>>(z, flatz, zb);
  prep_cb<<<NCODES / 4, 256, 0, stream>>>(cb, eb, enorm);
  vq_gemm<<<dim3(NCODES / 128, NROWS / 128), 256, 0, stream>>>(eb, zb, enorm, bm);
  vq_select<<<NROWS, 256, 0, stream>>>(bm, flatz, cb, enorm, zq, oidx);
}

// Round 2
// 285.001 us; speedup vs baseline: 1.5963x; 1.5963x over previous
//
#include <hip/hip_runtime.h>
#include <stdint.h>

#define NROWS 16384   // 16*32*32 spatial positions
#define NCODES 8192
#define DIM 256
#define MARGIN 1.0f   // ~7 sigma of bf16 dist-error difference; R1-validated

typedef __attribute__((ext_vector_type(8))) short bf16x8;  // 8 bf16 = 4 VGPRs
typedef __attribute__((ext_vector_type(4))) float f32x4;

__device__ __forceinline__ unsigned short f2bf(float f) {
  union { float f; unsigned int u; } v; v.f = f;
  unsigned int u = v.u;
  return (unsigned short)((u + 0x7FFFu + ((u >> 16) & 1u)) >> 16);  // RNE
}

// async global->LDS, 16B per lane; LDS dest = wave-uniform base + lane*16
__device__ __forceinline__ void glds16(const void* g, void* l) {
  __builtin_amdgcn_global_load_lds(
      (const __attribute__((address_space(1))) unsigned int*)g,
      (__attribute__((address_space(3))) unsigned int*)l, 16, 0, 0);
}

// order-preserving float->u32, packed with index; u64-min == (dist, lowest idx)
__device__ __forceinline__ unsigned long long packdi(float d, int idx) {
  unsigned int u = __float_as_uint(d);
  u = (u & 0x80000000u) ? ~u : (u | 0x80000000u);
  return ((unsigned long long)u << 32) | (unsigned int)idx;
}
__device__ __forceinline__ float unpackf(unsigned long long k) {
  unsigned int u = (unsigned int)(k >> 32);
  u = (u & 0x80000000u) ? (u & 0x7FFFFFFFu) : ~u;
  return __uint_as_float(u);
}
__device__ __forceinline__ unsigned long long u64min(unsigned long long a,
                                                     unsigned long long b) {
  return a < b ? a : b;
}
__device__ __forceinline__ unsigned long long shflx64(unsigned long long v, int m) {
  int lo = __shfl_xor((int)(unsigned int)v, m);
  int hi = __shfl_xor((int)(v >> 32), m);
  return ((unsigned long long)(unsigned int)hi << 32) | (unsigned int)lo;
}

// ---- Phase 0a: NCHW -> (row, d) transpose; write fp32 + bf16 copies --------
__global__ __launch_bounds__(256) void prep_z(const float* __restrict__ z,
                                              float* __restrict__ flatz,
                                              ushort* __restrict__ zb) {
  __shared__ float t[32][33];  // +1 pad: no bank conflicts
  const int tx = threadIdx.x & 31, ty = threadIdx.x >> 5;  // 32 x 8
  const int b = blockIdx.z, ct = blockIdx.y, ht = blockIdx.x;
  const float* src = z + (size_t)b * 262144 + (size_t)(ct * 32) * 1024 + ht * 32;
#pragma unroll
  for (int i = 0; i < 4; ++i) {
    int c = ty + i * 8;
    t[c][tx] = src[c * 1024 + tx];  // coalesced in hw
  }
  __syncthreads();
#pragma unroll
  for (int i = 0; i < 4; ++i) {
    int hw = ty + i * 8;
    int row = b * 1024 + ht * 32 + hw;
    float v = t[tx][hw];
    flatz[(size_t)row * 256 + ct * 32 + tx] = v;  // coalesced in d
    zb[(size_t)row * 256 + ct * 32 + tx] = f2bf(v);
  }
}

// ---- Phase 0b: codebook -> bf16 + fp32 ||e||^2 -----------------------------
__global__ __launch_bounds__(256) void prep_cb(const float* __restrict__ cb,
                                               ushort* __restrict__ eb,
                                               float* __restrict__ enorm) {
  const int lane = threadIdx.x & 63, wave = threadIdx.x >> 6;
  const int code = blockIdx.x * 4 + wave;
  float4 v = *(const float4*)(cb + (size_t)code * 256 + lane * 4);
  ushort4 o;
  o.x = f2bf(v.x); o.y = f2bf(v.y); o.z = f2bf(v.z); o.w = f2bf(v.w);
  *(ushort4*)(eb + (size_t)code * 256 + lane * 4) = o;
  float ss = v.x * v.x + v.y * v.y + v.z * v.z + v.w * v.w;
#pragma unroll
  for (int s = 1; s < 64; s <<= 1) ss += __shfl_xor(ss, s);
  if (lane == 0) enorm[code] = ss;
}

// ---- Phase 1: bf16 MFMA distance GEMM + per-(row, chunk64) min1/min2 -------
// A (MFMA M) = codebook tile, B (MFMA N) = z-row tile. 128x128 tile, BK=32,
// 4 waves each computing a 64x64 quadrant as 4x4 16x16x32 fragments.
// Epilogue stores bm[zrow][chunk] = pack(min dist, idx) AND bm2[zrow][chunk] =
// second-smallest dist in the chunk — lets Phase 2 prove argmin without
// recompute when the runner-up margin exceeds the bf16 error bound.
__global__ __launch_bounds__(256) void vq_gemm(const ushort* __restrict__ eb,
                                               const ushort* __restrict__ zb,
                                               const float* __restrict__ enorm,
                                               unsigned long long* __restrict__ bm,
                                               float* __restrict__ bm2) {
  __shared__ __align__(16) ushort As[128 * 32];  // codes x k, 8 KB
  __shared__ __align__(16) ushort Bs[128 * 32];  // zrows x k, 8 KB
  const int tid = threadIdx.x;
  const int wave = tid >> 6, lane = tid & 63;
  const int wr = wave >> 1, wc = wave & 1;  // code half / zrow half
  const int code0 = blockIdx.x * 128;
  const int zrow0 = blockIdx.y * 128;

  f32x4 acc[4][4] = {};  // [code frag i][zrow frag j]

  // staging map: LDS slot (l&3) of row (l>>2) holds global k-chunk
  // (l&3)^(row&3)  — XOR swizzle cuts ds_read_b128 conflicts 8-way -> 4-way
  const int r_in = lane >> 2;
  const int kc = (lane & 3) ^ (r_in & 3);
  ushort* As0 = As + wave * 512;        // each glds inst fills 16 rows (1 KB)
  ushort* As1 = As + (wave + 4) * 512;
  ushort* Bs0 = Bs + wave * 512;
  ushort* Bs1 = Bs + (wave + 4) * 512;
  const ushort* aG0 = eb + (size_t)(code0 + wave * 16 + r_in) * 256 + kc * 8;
  const ushort* aG1 = eb + (size_t)(code0 + 64 + wave * 16 + r_in) * 256 + kc * 8;
  const ushort* bG0 = zb + (size_t)(zrow0 + wave * 16 + r_in) * 256 + kc * 8;
  const ushort* bG1 = zb + (size_t)(zrow0 + 64 + wave * 16 + r_in) * 256 + kc * 8;

  const int q = lane >> 4;    // k-quad for A/B frags; row-quad for C/D
  const int l15 = lane & 15;
  const int slot = (q ^ (l15 & 3)) * 8;  // un-swizzle on read

  for (int k0 = 0; k0 < 8; ++k0) {
    glds16(aG0 + k0 * 32, As0);
    glds16(aG1 + k0 * 32, As1);
    glds16(bG0 + k0 * 32, Bs0);
    glds16(bG1 + k0 * 32, Bs1);
    __syncthreads();  // compiler drains vmcnt before s_barrier (m97 pattern)
    bf16x8 af[4], bf[4];
#pragma unroll
    for (int i = 0; i < 4; ++i)
      af[i] = *(const bf16x8*)(As + (wr * 64 + i * 16 + l15) * 32 + slot);
#pragma unroll
    for (int j = 0; j < 4; ++j)
      bf[j] = *(const bf16x8*)(Bs + (wc * 64 + j * 16 + l15) * 32 + slot);
#pragma unroll
    for (int i = 0; i < 4; ++i)
#pragma unroll
      for (int j = 0; j < 4; ++j)
        acc[i][j] = __builtin_amdgcn_mfma_f32_16x16x32_bf16(af[i], bf[j],
                                                            acc[i][j], 0, 0, 0);
    __syncthreads();  // protect LDS before next stage
  }

  // epilogue: dist = enorm - 2*dot ; C/D layout col=lane&15 (zrow), row=q*4+r (code)
  float en[4][4];
#pragma unroll
  for (int i = 0; i < 4; ++i) {
    float4 e = *(const float4*)(enorm + code0 + wr * 64 + i * 16 + q * 4);
    en[i][0] = e.x; en[i][1] = e.y; en[i][2] = e.z; en[i][3] = e.w;
  }
#pragma unroll
  for (int j = 0; j < 4; ++j) {
    float bd = 3.4e38f; int bi = 0; float b2 = 3.4e38f;
#pragma unroll
    for (int i = 0; i < 4; ++i)
#pragma unroll
      for (int r = 0; r < 4; ++r) {
        float d = fmaf(-2.f, acc[i][j][r], en[i][r]);
        int c = code0 + wr * 64 + i * 16 + q * 4 + r;  // ascending: tie keeps lowest
        if (d < bd) { b2 = bd; bd = d; bi = c; }
        else if (d < b2) { b2 = d; }
      }
    unsigned long long key = packdi(bd, bi);
#pragma unroll
    for (int m = 16; m < 64; m <<= 1) {  // merge the 4 q-groups (same zrow set)
      unsigned long long ok = shflx64(key, m);
      float o2 = __shfl_xor(b2, m);
      float loser = unpackf(key > ok ? key : ok);  // larger min1 becomes a 2nd cand
      b2 = fminf(fminf(b2, o2), loser);
      key = u64min(key, ok);
    }
    if (lane < 16) {
      int zr = zrow0 + wc * 64 + j * 16 + lane;
      bm[(size_t)zr * 128 + blockIdx.x * 2 + wr] = key;
      bm2[(size_t)zr * 128 + blockIdx.x * 2 + wr] = b2;
    }
  }
}

// ---- Phase 2: margin test + (rare) fp32 refinement + gather ----------------
// One block per row. Global best over 128 chunk minima; runner-up =
// min(best-of-other-chunks, second-of-winning-chunk). If runner - best >
// MARGIN, the bf16 argmin is provably the fp32 argmin — no recompute, just
// gather. Else recompute every chunk within the window exactly in fp32
// (lowest-index tie-break matches numpy argmin).
__global__ __launch_bounds__(256) void vq_select(
    const unsigned long long* __restrict__ bm, const float* __restrict__ bm2,
    const float* __restrict__ flatz, const float* __restrict__ cb,
    const float* __restrict__ enorm, float* __restrict__ zq,
    float* __restrict__ oidx) {
  __shared__ unsigned long long skey[4];
  __shared__ float s2[4];
  __shared__ unsigned long long cmask[4];
  __shared__ unsigned long long sbest;
  __shared__ int sfast;
  const int row = blockIdx.x;
  const int tid = threadIdx.x, lane = tid & 63, wave = tid >> 6;

  const unsigned long long e =
      (tid < 128) ? bm[(size_t)row * 128 + tid] : packdi(3.4e38f, 0x7FFFFFFF);
  unsigned long long k1 = e;
  float d2 = 3.4e38f;  // runner-up among chunk minima
#pragma unroll
  for (int s = 1; s < 64; s <<= 1) {
    unsigned long long ok = shflx64(k1, s);
    float o2 = __shfl_xor(d2, s);
    float loser = unpackf(k1 > ok ? k1 : ok);
    d2 = fminf(fminf(d2, o2), loser);
    k1 = u64min(k1, ok);
  }
  if (lane == 0) { skey[wave] = k1; s2[wave] = d2; }
  __syncthreads();
  if (tid == 0) {
    unsigned long long k = skey[0]; float dd = s2[0];
#pragma unroll
    for (int w = 1; w < 4; ++w) {
      unsigned long long ok = skey[w];
      float loser = unpackf(k > ok ? k : ok);
      dd = fminf(fminf(dd, s2[w]), loser);
      k = u64min(k, ok);
    }
    int idx = (int)(k & 0xFFFFFFFFull);
    float best = unpackf(k);
    float runner = fminf(dd, bm2[(size_t)row * 128 + (idx >> 6)]);
    sbest = k;
    sfast = (runner - best > MARGIN) ? idx : -1;
  }
  __syncthreads();

  int idx = sfast;
  if (idx < 0) {  // block-uniform slow path (~10% of rows)
    float thr = unpackf(sbest) + MARGIN;
    unsigned long long bal = __ballot(tid < 128 && unpackf(e) <= thr);
    if (lane == 0) cmask[wave] = bal;  // waves 2,3 contribute 0
    __syncthreads();

    float bd = 3.4e38f; int bi = -1;
    const float* zp = flatz + (size_t)row * 256 + (tid & 3) * 64;
    for (int half = 0; half < 2; ++half) {
      unsigned long long mask = cmask[half];
      while (mask) {
        int b = __ffsll(mask) - 1;
        mask &= mask - 1;
        int code = (half * 64 + b) * 64 + (tid >> 2);  // 4 threads per code
        const float* cp = cb + (size_t)code * 256 + (tid & 3) * 64;
        float s = 0.f;
#pragma unroll
        for (int d = 0; d < 64; d += 4) {
          float4 zv = *(const float4*)(zp + d);
          float4 cv = *(const float4*)(cp + d);
          s = fmaf(zv.x, cv.x, s); s = fmaf(zv.y, cv.y, s);
          s = fmaf(zv.z, cv.z, s); s = fmaf(zv.w, cv.w, s);
        }
        s += __shfl_xor(s, 1);
        s += __shfl_xor(s, 2);
        if ((tid & 3) == 0) {
          float d = fmaf(-2.f, s, enorm[code]);
          if (d < bd) { bd = d; bi = code; }  // ascending order: tie keeps lowest
        }
      }
    }
    unsigned long long key = (bi >= 0) ? packdi(bd, bi) : ~0ull;
#pragma unroll
    for (int s = 1; s < 64; s <<= 1) key = u64min(key, shflx64(key, s));
    if (lane == 0) skey[wave] = key;
    __syncthreads();
    if (tid == 0)
      sbest = u64min(u64min(skey[0], skey[1]), u64min(skey[2], skey[3]));
    __syncthreads();
    idx = (int)(sbest & 0xFFFFFFFFull);
  }

  if (tid == 0) oidx[row] = (float)idx;
  zq[(size_t)row * 256 + tid] = cb[(size_t)idx * 256 + tid];  // exact fp32 gather
}

// ---- launch ----------------------------------------------------------------
extern "C" void kernel_launch(void* const* d_in, const int* in_sizes, int n_in,
                              void* d_out, int out_size, void* d_ws, size_t ws_size,
                              hipStream_t stream) {
  const float* z = (const float*)d_in[0];   // (16,256,32,32) fp32
  const float* cb = (const float*)d_in[1];  // (8192,256) fp32
  char* ws = (char*)d_ws;
  // ws: zb 8M | eb 4M | enorm 32K | flatz 16M @13M | bm 16M @29M | bm2 8M @45M
  ushort* zb = (ushort*)(ws);
  ushort* eb = (ushort*)(ws + (8u << 20));
  float* enorm = (float*)(ws + (12u << 20));
  float* flatz = (float*)(ws + (13u << 20));
  unsigned long long* bm = (unsigned long long*)(ws + (29u << 20));
  float* bm2 = (float*)(ws + (45u << 20));
  float* zq = (float*)d_out;                      // (16384,256) fp32
  float* oidx = zq + (size_t)NROWS * DIM;         // (16384,) as fp32 values

  prep_z<<<dim3(32, 8, 16), 256, 0, stream>>>(z, flatz, zb);
  prep_cb<<<NCODES / 4, 256, 0, stream>>>(cb, eb, enorm);
  vq_gemm<<<dim3(NCODES / 128, NROWS / 128), 256, 0, stream>>>(eb, zb, enorm, bm, bm2);
  vq_select<<<NROWS, 256, 0, stream>>>(bm, bm2, flatz, cb, enorm, zq, oidx);
}

// Round 3
// 269.317 us; speedup vs baseline: 1.6893x; 1.0582x over previous
//
#include <hip/hip_runtime.h>
#include <stdint.h>

#define NROWS 16384   // 16*32*32 spatial positions
#define NCODES 8192
#define DIM 256
#define SMARGIN 0.55f // score-space margin: 0.5 (== dist 1.0, R1/R2-validated) + pack slack

typedef __attribute__((ext_vector_type(8))) short bf16x8;  // 8 bf16 = 4 VGPRs
typedef __attribute__((ext_vector_type(4))) float f32x4;
typedef unsigned int uint32;

__device__ __forceinline__ unsigned short f2bf(float f) {
  union { float f; unsigned int u; } v; v.f = f;
  unsigned int u = v.u;
  return (unsigned short)((u + 0x7FFFu + ((u >> 16) & 1u)) >> 16);  // RNE
}

__device__ __forceinline__ void glds16(const void* g, void* l) {
  __builtin_amdgcn_global_load_lds(
      (const __attribute__((address_space(1))) unsigned int*)g,
      (__attribute__((address_space(3))) unsigned int*)l, 16, 0, 0);
}

// exact-path helpers (u64 key = order-preserving dist bits << 32 | idx)
__device__ __forceinline__ unsigned long long packdi(float d, int idx) {
  unsigned int u = __float_as_uint(d);
  u = (u & 0x80000000u) ? ~u : (u | 0x80000000u);
  return ((unsigned long long)u << 32) | (unsigned int)idx;
}
__device__ __forceinline__ unsigned long long u64min(unsigned long long a,
                                                     unsigned long long b) {
  return a < b ? a : b;
}
__device__ __forceinline__ unsigned long long shflx64(unsigned long long v, int m) {
  int lo = __shfl_xor((int)(unsigned int)v, m);
  int hi = __shfl_xor((int)(v >> 32), m);
  return ((unsigned long long)(unsigned int)hi << 32) | (unsigned int)lo;
}
__device__ __forceinline__ uint32 umax(uint32 a, uint32 b) { return a > b ? a : b; }
__device__ __forceinline__ uint32 umin(uint32 a, uint32 b) { return a < b ? a : b; }

// ---- Phase 0a: NCHW -> (row, d) transpose; write fp32 + bf16 copies --------
__global__ __launch_bounds__(256) void prep_z(const float* __restrict__ z,
                                              float* __restrict__ flatz,
                                              ushort* __restrict__ zb) {
  __shared__ float t[32][33];
  const int tx = threadIdx.x & 31, ty = threadIdx.x >> 5;  // 32 x 8
  const int b = blockIdx.z, ct = blockIdx.y, ht = blockIdx.x;
  const float* src = z + (size_t)b * 262144 + (size_t)(ct * 32) * 1024 + ht * 32;
#pragma unroll
  for (int i = 0; i < 4; ++i) {
    int c = ty + i * 8;
    t[c][tx] = src[c * 1024 + tx];
  }
  __syncthreads();
#pragma unroll
  for (int i = 0; i < 4; ++i) {
    int hw = ty + i * 8;
    int row = b * 1024 + ht * 32 + hw;
    float v = t[tx][hw];
    flatz[(size_t)row * 256 + ct * 32 + tx] = v;
    zb[(size_t)row * 256 + ct * 32 + tx] = f2bf(v);
  }
}

// ---- Phase 0b: codebook -> bf16 + fp32 ||e||^2 -----------------------------
__global__ __launch_bounds__(256) void prep_cb(const float* __restrict__ cb,
                                               ushort* __restrict__ eb,
                                               float* __restrict__ enorm) {
  const int lane = threadIdx.x & 63, wave = threadIdx.x >> 6;
  const int code = blockIdx.x * 4 + wave;
  float4 v = *(const float4*)(cb + (size_t)code * 256 + lane * 4);
  ushort4 o;
  o.x = f2bf(v.x); o.y = f2bf(v.y); o.z = f2bf(v.z); o.w = f2bf(v.w);
  *(ushort4*)(eb + (size_t)code * 256 + lane * 4) = o;
  float ss = v.x * v.x + v.y * v.y + v.z * v.z + v.w * v.w;
#pragma unroll
  for (int s = 1; s < 64; s <<= 1) ss += __shfl_xor(ss, s);
  if (lane == 0) enorm[code] = ss;
}

// ---- Phase 1: bf16 MFMA score GEMM + per-(row, chunk64) packed top-2 -------
// score = 1024 + dot - ||e||^2/2 (acc-init trick): argmin dist == argmax score.
// All scores in (0,2048) -> positive-float bit pattern is order-preserving as
// u32. Low 6 mantissa bits are overwritten with the intra-chunk code id (error
// <= 2^-7, absorbed in SMARGIN slack). Epilogue keeps per-chunk max1(+id) and
// exact max2 so Phase 2 can prove the argmin without recompute.
// Double-buffered LDS: one barrier per K-iter; glds(k+1) drains at barrier k+1.
__global__ __launch_bounds__(256) void vq_gemm(const ushort* __restrict__ eb,
                                               const ushort* __restrict__ zb,
                                               const float* __restrict__ enorm,
                                               uint32* __restrict__ bm,
                                               uint32* __restrict__ bm2) {
  __shared__ __align__(16) ushort As[2][4096];  // 2 x (128 codes x 32 k) = 16 KB
  __shared__ __align__(16) ushort Bs[2][4096];  // 2 x (128 zrows x 32 k)
  const int tid = threadIdx.x;
  const int wave = tid >> 6, lane = tid & 63;
  const int wr = wave >> 1, wc = wave & 1;  // code half / zrow half
  const int code0 = blockIdx.x * 128;
  const int zrow0 = blockIdx.y * 128;

  const int q = lane >> 4;    // k-quad for A/B frags; row-quad for C/D
  const int l15 = lane & 15;
  const int slot = (q ^ (l15 & 3)) * 8;  // un-swizzle on read

  // acc init: 1024 - 0.5*||e||^2 replicated across the 4 zrow frags
  f32x4 acc[4][4];
#pragma unroll
  for (int i = 0; i < 4; ++i) {
    float4 e = *(const float4*)(enorm + code0 + wr * 64 + i * 16 + q * 4);
    f32x4 c0 = {1024.f - 0.5f * e.x, 1024.f - 0.5f * e.y,
                1024.f - 0.5f * e.z, 1024.f - 0.5f * e.w};
#pragma unroll
    for (int j = 0; j < 4; ++j) acc[i][j] = c0;
  }

  // staging: LDS slot (l&3) of row (l>>2) holds global k-chunk (l&3)^(row&3)
  const int r_in = lane >> 2;
  const int kc = (lane & 3) ^ (r_in & 3);
  const ushort* aG0 = eb + (size_t)(code0 + wave * 16 + r_in) * 256 + kc * 8;
  const ushort* aG1 = eb + (size_t)(code0 + 64 + wave * 16 + r_in) * 256 + kc * 8;
  const ushort* bG0 = zb + (size_t)(zrow0 + wave * 16 + r_in) * 256 + kc * 8;
  const ushort* bG1 = zb + (size_t)(zrow0 + 64 + wave * 16 + r_in) * 256 + kc * 8;

  // prologue: stage k0=0 into buffer 0
  glds16(aG0, &As[0][wave * 512]);
  glds16(aG1, &As[0][(wave + 4) * 512]);
  glds16(bG0, &Bs[0][wave * 512]);
  glds16(bG1, &Bs[0][(wave + 4) * 512]);

#pragma unroll
  for (int k0 = 0; k0 < 8; ++k0) {
    const int cur = k0 & 1;
    __syncthreads();  // drains vmcnt: stage(k0) done; all reads of buf cur done
    if (k0 < 7) {
      const int nxt = cur ^ 1;
      glds16(aG0 + (k0 + 1) * 32, &As[nxt][wave * 512]);
      glds16(aG1 + (k0 + 1) * 32, &As[nxt][(wave + 4) * 512]);
      glds16(bG0 + (k0 + 1) * 32, &Bs[nxt][wave * 512]);
      glds16(bG1 + (k0 + 1) * 32, &Bs[nxt][(wave + 4) * 512]);
    }
    bf16x8 af[4], bf[4];
#pragma unroll
    for (int i = 0; i < 4; ++i)
      af[i] = *(const bf16x8*)(&As[cur][(wr * 64 + i * 16 + l15) * 32 + slot]);
#pragma unroll
    for (int j = 0; j < 4; ++j)
      bf[j] = *(const bf16x8*)(&Bs[cur][(wc * 64 + j * 16 + l15) * 32 + slot]);
#pragma unroll
    for (int i = 0; i < 4; ++i)
#pragma unroll
      for (int j = 0; j < 4; ++j)
        acc[i][j] = __builtin_amdgcn_mfma_f32_16x16x32_bf16(af[i], bf[j],
                                                            acc[i][j], 0, 0, 0);
  }

  // epilogue: C/D layout col=lane&15 (zrow), row=q*4+r (code within 16-frag).
  // packed value = (score bits & ~63) | intra-chunk code (i*16 + q*4 + r).
  const uint32 blane = (uint32)(q * 4);  // bits [3:2]
  const int cid = blockIdx.x * 2 + wr;   // 64-code chunk id
#pragma unroll
  for (int j = 0; j < 4; ++j) {
    uint32 m1 = 0, m2 = 0;
#pragma unroll
    for (int i = 0; i < 4; ++i)
#pragma unroll
      for (int r = 0; r < 4; ++r) {
        uint32 pv = (__float_as_uint(acc[i][j][r]) & ~63u) | blane |
                    (uint32)(i * 16 + r);
        m2 = umax(m2, umin(m1, pv));
        m1 = umax(m1, pv);
      }
#pragma unroll
    for (int m = 16; m < 64; m <<= 1) {  // merge 4 q-groups (same zrow set)
      uint32 o1 = (uint32)__shfl_xor((int)m1, m);
      uint32 o2 = (uint32)__shfl_xor((int)m2, m);
      m2 = umax(umax(m2, o2), umin(m1, o1));
      m1 = umax(m1, o1);
    }
    if (lane < 16) {
      int zr = zrow0 + wc * 64 + j * 16 + lane;
      bm[(size_t)zr * 128 + cid] = m1;
      bm2[(size_t)zr * 128 + cid] = m2;
    }
  }
}

// ---- Phase 2a: wave-per-row margin test + gather; compact slow rows --------
__global__ __launch_bounds__(256) void vq_sel1(const uint32* __restrict__ bm,
                                               const uint32* __restrict__ bm2,
                                               const float* __restrict__ cb,
                                               float* __restrict__ zq,
                                               float* __restrict__ oidx,
                                               int* __restrict__ slowlist,
                                               int* __restrict__ counter) {
  const int lane = threadIdx.x & 63, w = threadIdx.x >> 6;
  const int row = blockIdx.x * 4 + w;
  uint32 a = bm[(size_t)row * 128 + lane];
  uint32 b = bm[(size_t)row * 128 + 64 + lane];
  uint32 m1 = umax(a, b), m2 = umin(a, b);
  uint32 ch = (b > a) ? (uint32)(64 + lane) : (uint32)lane;
#pragma unroll
  for (int m = 1; m < 64; m <<= 1) {
    uint32 o1 = (uint32)__shfl_xor((int)m1, m);
    uint32 o2 = (uint32)__shfl_xor((int)m2, m);
    uint32 oc = (uint32)__shfl_xor((int)ch, m);
    m2 = umax(umax(m2, o2), umin(m1, o1));
    ch = (o1 > m1) ? oc : ch;
    m1 = umax(m1, o1);
  }
  uint32 runner = umax(m2, bm2[(size_t)row * 128 + ch]);
  float bestf = __uint_as_float(m1);
  float runnf = __uint_as_float(runner);
  int code = (int)(ch * 64 + (m1 & 63u));
  if (bestf - runnf > SMARGIN) {  // provable: approx argmax == exact argmin
    if (lane == 0) oidx[row] = (float)code;
    *(float4*)(zq + (size_t)row * 256 + lane * 4) =
        *(const float4*)(cb + (size_t)code * 256 + lane * 4);
  } else if (lane == 0) {
    int p = atomicAdd(counter, 1);
    slowlist[p] = row;
  }
}

// ---- Phase 2b: exact fp32 recompute for compacted slow rows ----------------
// Math kept identical to the R2 slow path (same thread split / summation
// order / lowest-index tie-break) which passed with absmax 0.
__global__ __launch_bounds__(256) void vq_sel2(
    const int* __restrict__ counter, const int* __restrict__ slowlist,
    const uint32* __restrict__ bm, const float* __restrict__ flatz,
    const float* __restrict__ cb, const float* __restrict__ enorm,
    float* __restrict__ zq, float* __restrict__ oidx) {
  __shared__ uint32 sm[4];
  __shared__ unsigned long long cmask[2];
  __shared__ unsigned long long skey[4];
  __shared__ unsigned long long sfin;
  const int tid = threadIdx.x, lane = tid & 63, wave = tid >> 6;
  const int n = *counter;
  for (int it = blockIdx.x; it < n; it += gridDim.x) {
    const int row = slowlist[it];
    uint32 c = (tid < 128) ? bm[(size_t)row * 128 + tid] : 0u;
    uint32 m1 = c;
#pragma unroll
    for (int s = 1; s < 64; s <<= 1) m1 = umax(m1, (uint32)__shfl_xor((int)m1, s));
    if (lane == 0) sm[wave] = m1;
    __syncthreads();
    uint32 best = umax(umax(sm[0], sm[1]), umax(sm[2], sm[3]));
    float thr = __uint_as_float(best) - SMARGIN;
    unsigned long long bal = __ballot(tid < 128 && __uint_as_float(c) >= thr);
    if (lane == 0 && wave < 2) cmask[wave] = bal;
    __syncthreads();

    float bd = 3.4e38f; int bi = -1;
    const float* zp = flatz + (size_t)row * 256 + (tid & 3) * 64;
    for (int half = 0; half < 2; ++half) {
      unsigned long long mask = cmask[half];
      while (mask) {
        int b = __ffsll(mask) - 1;
        mask &= mask - 1;
        int code = (half * 64 + b) * 64 + (tid >> 2);  // 4 threads per code
        const float* cp = cb + (size_t)code * 256 + (tid & 3) * 64;
        float s = 0.f;
#pragma unroll
        for (int d = 0; d < 64; d += 4) {
          float4 zv = *(const float4*)(zp + d);
          float4 cv = *(const float4*)(cp + d);
          s = fmaf(zv.x, cv.x, s); s = fmaf(zv.y, cv.y, s);
          s = fmaf(zv.z, cv.z, s); s = fmaf(zv.w, cv.w, s);
        }
        s += __shfl_xor(s, 1);
        s += __shfl_xor(s, 2);
        if ((tid & 3) == 0) {
          float d = fmaf(-2.f, s, enorm[code]);
          if (d < bd) { bd = d; bi = code; }  // ascending: tie keeps lowest
        }
      }
    }
    unsigned long long key = (bi >= 0) ? packdi(bd, bi) : ~0ull;
#pragma unroll
    for (int s = 1; s < 64; s <<= 1) key = u64min(key, shflx64(key, s));
    if (lane == 0) skey[wave] = key;
    __syncthreads();
    if (tid == 0)
      sfin = u64min(u64min(skey[0], skey[1]), u64min(skey[2], skey[3]));
    __syncthreads();
    int idx = (int)(sfin & 0xFFFFFFFFull);
    if (tid == 0) oidx[row] = (float)idx;
    zq[(size_t)row * 256 + tid] = cb[(size_t)idx * 256 + tid];
    __syncthreads();  // protect shared state before next list item
  }
}

// ---- launch ----------------------------------------------------------------
extern "C" void kernel_launch(void* const* d_in, const int* in_sizes, int n_in,
                              void* d_out, int out_size, void* d_ws, size_t ws_size,
                              hipStream_t stream) {
  const float* z = (const float*)d_in[0];   // (16,256,32,32) fp32
  const float* cb = (const float*)d_in[1];  // (8192,256) fp32
  char* ws = (char*)d_ws;
  // ws: zb 8M@0 | eb 4M@8M | enorm 32K@12M | flatz 16M@13M | bm 8M@29M |
  //     bm2 8M@37M | slowlist 64K@45M | counter 4B after
  ushort* zb = (ushort*)(ws);
  ushort* eb = (ushort*)(ws + (8u << 20));
  float* enorm = (float*)(ws + (12u << 20));
  float* flatz = (float*)(ws + (13u << 20));
  uint32* bm = (uint32*)(ws + (29u << 20));
  uint32* bm2 = (uint32*)(ws + (37u << 20));
  int* slowlist = (int*)(ws + (45u << 20));
  int* counter = (int*)(ws + (45u << 20) + 65536);
  float* zq = (float*)d_out;                      // (16384,256) fp32
  float* oidx = zq + (size_t)NROWS * DIM;         // (16384,) as fp32 values

  hipMemsetAsync(counter, 0, sizeof(int), stream);
  prep_z<<<dim3(32, 8, 16), 256, 0, stream>>>(z, flatz, zb);
  prep_cb<<<NCODES / 4, 256, 0, stream>>>(cb, eb, enorm);
  vq_gemm<<<dim3(NCODES / 128, NROWS / 128), 256, 0, stream>>>(eb, zb, enorm, bm, bm2);
  vq_sel1<<<NROWS / 4, 256, 0, stream>>>(bm, bm2, cb, zq, oidx, slowlist, counter);
  vq_sel2<<<2048, 256, 0, stream>>>(counter, slowlist, bm, flatz, cb, enorm, zq, oidx);
}

// Round 4
// 254.804 us; speedup vs baseline: 1.7855x; 1.0570x over previous
//
#include <hip/hip_runtime.h>
#include <stdint.h>

#define NROWS 16384   // 16*32*32 spatial positions
#define NCODES 8192
#define DIM 256
// score = 1024 + dot - ||e||^2/2  (higher = closer). bf16 dist-error sigma
// ~0.1 => score sigma ~0.05. EPS_S = 0.4 (8 sigma, one-sided); SM = 0.8
// (margin between two approx scores). Dist-space equivalents 0.8 / 1.6.
#define EPS_S 0.4f
#define SM 0.8f

typedef __attribute__((ext_vector_type(8))) short bf16x8;  // 8 bf16 = 4 VGPRs
typedef __attribute__((ext_vector_type(4))) float f32x4;
typedef unsigned int uint32;

__device__ __forceinline__ unsigned short f2bf(float f) {
  union { float f; unsigned int u; } v; v.f = f;
  unsigned int u = v.u;
  return (unsigned short)((u + 0x7FFFu + ((u >> 16) & 1u)) >> 16);  // RNE
}

__device__ __forceinline__ void glds16(const void* g, void* l) {
  __builtin_amdgcn_global_load_lds(
      (const __attribute__((address_space(1))) unsigned int*)g,
      (__attribute__((address_space(3))) unsigned int*)l, 16, 0, 0);
}

// exact-path u64 key = order-preserving dist bits << 32 | idx (min = best+lowest idx)
__device__ __forceinline__ unsigned long long packdi(float d, int idx) {
  unsigned int u = __float_as_uint(d);
  u = (u & 0x80000000u) ? ~u : (u | 0x80000000u);
  return ((unsigned long long)u << 32) | (unsigned int)idx;
}
__device__ __forceinline__ unsigned long long u64min(unsigned long long a,
                                                     unsigned long long b) {
  return a < b ? a : b;
}
__device__ __forceinline__ unsigned long long shflx64(unsigned long long v, int m) {
  int lo = __shfl_xor((int)(unsigned int)v, m);
  int hi = __shfl_xor((int)(v >> 32), m);
  return ((unsigned long long)(unsigned int)hi << 32) | (unsigned int)lo;
}
__device__ __forceinline__ uint32 umax(uint32 a, uint32 b) { return a > b ? a : b; }
__device__ __forceinline__ uint32 umin(uint32 a, uint32 b) { return a < b ? a : b; }

// ---- Phase 0a: NCHW -> (row, d) transpose; fp32 copy lives in zq (d_out) ---
__global__ __launch_bounds__(256) void prep_z(const float* __restrict__ z,
                                              float* __restrict__ flatz,
                                              ushort* __restrict__ zb) {
  __shared__ float t[32][33];
  const int tx = threadIdx.x & 31, ty = threadIdx.x >> 5;  // 32 x 8
  const int b = blockIdx.z, ct = blockIdx.y, ht = blockIdx.x;
  const float* src = z + (size_t)b * 262144 + (size_t)(ct * 32) * 1024 + ht * 32;
#pragma unroll
  for (int i = 0; i < 4; ++i) {
    int c = ty + i * 8;
    t[c][tx] = src[c * 1024 + tx];
  }
  __syncthreads();
#pragma unroll
  for (int i = 0; i < 4; ++i) {
    int hw = ty + i * 8;
    int row = b * 1024 + ht * 32 + hw;
    float v = t[tx][hw];
    flatz[(size_t)row * 256 + ct * 32 + tx] = v;
    zb[(size_t)row * 256 + ct * 32 + tx] = f2bf(v);
  }
}

// ---- Phase 0b: codebook -> bf16 + fp32 ||e||^2 -----------------------------
__global__ __launch_bounds__(256) void prep_cb(const float* __restrict__ cb,
                                               ushort* __restrict__ eb,
                                               float* __restrict__ enorm) {
  const int lane = threadIdx.x & 63, wave = threadIdx.x >> 6;
  const int code = blockIdx.x * 4 + wave;
  float4 v = *(const float4*)(cb + (size_t)code * 256 + lane * 4);
  ushort4 o;
  o.x = f2bf(v.x); o.y = f2bf(v.y); o.z = f2bf(v.z); o.w = f2bf(v.w);
  *(ushort4*)(eb + (size_t)code * 256 + lane * 4) = o;
  float ss = v.x * v.x + v.y * v.y + v.z * v.z + v.w * v.w;
#pragma unroll
  for (int s = 1; s < 64; s <<= 1) ss += __shfl_xor(ss, s);
  if (lane == 0) enorm[code] = ss;
}

// ---- Phase 1: MFMA score GEMM. A(codes) via LDS dbuf; B(zrows) straight ----
// from global (one 16B load = 16 rows x 64B lines, zero over-fetch, no LDS).
// Tile: 128 codes x 256 zrows, 4 waves = (wr: code half) x (wc: zrow half),
// each wave 64x128 = 4i x 8j frags of 16x16x32. Epilogue: per 16-code chunk
// (== one i-frag) store packed u32: score bits & ~31 | gapflag<<4 | id(4b).
__global__ __launch_bounds__(256, 2) void vq_gemm(const ushort* __restrict__ eb,
                                                  const ushort* __restrict__ zb,
                                                  const float* __restrict__ enorm,
                                                  uint32* __restrict__ bm) {
  __shared__ __align__(16) ushort As[2][4096];  // 2 x (128 codes x 32 k) = 16 KB
  const int tid = threadIdx.x;
  const int wave = tid >> 6, lane = tid & 63;
  const int wr = wave >> 1, wc = wave & 1;
  const int code0 = blockIdx.x * 128;
  const int zrow0 = blockIdx.y * 256;
  const int q = lane >> 4, l15 = lane & 15;
  const int slot = (q ^ (l15 & 3)) * 8;  // un-swizzle A on read

  // acc init: 1024 - 0.5*||e||^2 (score trick) replicated across 8 j-frags
  f32x4 acc[4][8];
#pragma unroll
  for (int i = 0; i < 4; ++i) {
    float4 e = *(const float4*)(enorm + code0 + wr * 64 + i * 16 + q * 4);
    f32x4 c0 = {1024.f - 0.5f * e.x, 1024.f - 0.5f * e.y,
                1024.f - 0.5f * e.z, 1024.f - 0.5f * e.w};
#pragma unroll
    for (int j = 0; j < 8; ++j) acc[i][j] = c0;
  }

  // A staging (XOR-swizzled k-chunks, as validated in R2/R3)
  const int r_in = lane >> 2;
  const int kc = (lane & 3) ^ (r_in & 3);
  const ushort* aG0 = eb + (size_t)(code0 + wave * 16 + r_in) * 256 + kc * 8;
  const ushort* aG1 = eb + (size_t)(code0 + 64 + wave * 16 + r_in) * 256 + kc * 8;
  glds16(aG0, &As[0][wave * 512]);
  glds16(aG1, &As[0][(wave + 4) * 512]);

  // B global bases: frag j covers zrows zrow0+wc*128+j*16..+15, lane reads
  // 16B at row l15, k-offset q*8 (+k0*32 per iter, 64B imm offsets)
  const ushort* bG[8];
#pragma unroll
  for (int j = 0; j < 8; ++j)
    bG[j] = zb + (size_t)(zrow0 + wc * 128 + j * 16 + l15) * 256 + q * 8;

#pragma unroll
  for (int k0 = 0; k0 < 8; ++k0) {
    const int cur = k0 & 1;
    __syncthreads();  // drains glds of stage k0 (and prior B loads)
    if (k0 < 7) {
      glds16(aG0 + (k0 + 1) * 32, &As[cur ^ 1][wave * 512]);
      glds16(aG1 + (k0 + 1) * 32, &As[cur ^ 1][(wave + 4) * 512]);
    }
    bf16x8 bf[8];
#pragma unroll
    for (int j = 0; j < 8; ++j)
      bf[j] = *(const bf16x8*)(bG[j] + k0 * 32);
    bf16x8 af[4];
#pragma unroll
    for (int i = 0; i < 4; ++i)
      af[i] = *(const bf16x8*)(&As[cur][(wr * 64 + i * 16 + l15) * 32 + slot]);
#pragma unroll
    for (int i = 0; i < 4; ++i)
#pragma unroll
      for (int j = 0; j < 8; ++j)
        acc[i][j] = __builtin_amdgcn_mfma_f32_16x16x32_bf16(af[i], bf[j],
                                                            acc[i][j], 0, 0, 0);
  }

  // epilogue: C/D col=lane&15 (zrow), row=q*4+r (code-in-chunk). Pack id low
  // 4 bits (ties collide -> demoted to exact path in vq_sel), top-2 chains,
  // flag bit 4 = in-chunk gap > SM.
  const int cid0 = blockIdx.x * 8 + wr * 4;
#pragma unroll
  for (int j = 0; j < 8; ++j) {
    uint32 res[4];
#pragma unroll
    for (int i = 0; i < 4; ++i) {
      uint32 pv0 = (__float_as_uint(acc[i][j][0]) & ~31u) | (uint32)(q * 4 + 0);
      uint32 pv1 = (__float_as_uint(acc[i][j][1]) & ~31u) | (uint32)(q * 4 + 1);
      uint32 pv2 = (__float_as_uint(acc[i][j][2]) & ~31u) | (uint32)(q * 4 + 2);
      uint32 pv3 = (__float_as_uint(acc[i][j][3]) & ~31u) | (uint32)(q * 4 + 3);
      uint32 x01 = umax(pv0, pv1), n01 = umin(pv0, pv1);
      uint32 x23 = umax(pv2, pv3), n23 = umin(pv2, pv3);
      uint32 m1 = umax(x01, x23);
      uint32 m2 = umax(umin(x01, x23), umax(n01, n23));
#pragma unroll
      for (int m = 16; m < 64; m <<= 1) {  // merge the 4 q-groups
        uint32 o1 = (uint32)__shfl_xor((int)m1, m);
        uint32 o2 = (uint32)__shfl_xor((int)m2, m);
        m2 = umax(umax(m2, o2), umin(m1, o1));
        m1 = umax(m1, o1);
      }
      float s1 = __uint_as_float(m1 & ~31u);
      float s2 = __uint_as_float(m2 & ~31u);
      res[i] = (s1 - s2 > SM) ? (m1 | 16u) : m1;
    }
    if (lane < 16) {
      int zr = zrow0 + wc * 128 + j * 16 + l15;
      uint4 o; o.x = res[0]; o.y = res[1]; o.z = res[2]; o.w = res[3];
      *(uint4*)(bm + (size_t)zr * 512 + cid0) = o;
    }
  }
}

// exact fp32 distances for one 16-code chunk; summation order / lane split /
// tie-break bit-identical to the R2/R3-validated slow path.
__device__ __forceinline__ unsigned long long chunk_exact(
    int chunk, const float* __restrict__ zrow, const float* __restrict__ cb,
    const float* __restrict__ enorm, int lane) {
  const int code = chunk * 16 + (lane >> 2);
  const float* zp = zrow + (lane & 3) * 64;
  const float* cp = cb + (size_t)code * 256 + (lane & 3) * 64;
  float s = 0.f;
#pragma unroll
  for (int d = 0; d < 64; d += 4) {
    float4 zv = *(const float4*)(zp + d);
    float4 cv = *(const float4*)(cp + d);
    s = fmaf(zv.x, cv.x, s); s = fmaf(zv.y, cv.y, s);
    s = fmaf(zv.z, cv.z, s); s = fmaf(zv.w, cv.w, s);
  }
  s += __shfl_xor(s, 1);
  s += __shfl_xor(s, 2);
  float dist = fmaf(-2.f, s, enorm[code]);
  unsigned long long key = ((lane & 3) == 0) ? packdi(dist, code) : ~0ull;
#pragma unroll
  for (int m = 1; m < 64; m <<= 1) key = u64min(key, shflx64(key, m));
  return key;  // wave-uniform
}

// ---- Phase 2: one wave per row ---------------------------------------------
// Top-2 + argmax over 512 chunk16 maxima. Fast path (winner flag set AND
// global margin > SM): index proven exact, zero recompute. Slow path: exact
// fp32 winner chunk, then exact recompute of every chunk within EPS_S window.
// flatz aliases zq (read own row fully before overwriting it — same wave).
__global__ __launch_bounds__(256) void vq_sel(const uint32* __restrict__ bm,
                                              const float* __restrict__ flatz,
                                              const float* __restrict__ cb,
                                              const float* __restrict__ enorm,
                                              float* __restrict__ zq,
                                              float* __restrict__ oidx) {
  const int lane = threadIdx.x & 63;
  const int row = blockIdx.x * 4 + (threadIdx.x >> 6);
  uint4 va = *(const uint4*)(bm + (size_t)row * 512 + lane * 8);
  uint4 vb = *(const uint4*)(bm + (size_t)row * 512 + lane * 8 + 4);
  uint32 v[8] = {va.x, va.y, va.z, va.w, vb.x, vb.y, vb.z, vb.w};
  uint32 m1 = 0, m2 = 0; int ch = 0;
#pragma unroll
  for (int s = 0; s < 8; ++s) {
    uint32 pv = v[s];
    m2 = umax(m2, umin(m1, pv));
    ch = (pv > m1) ? (lane * 8 + s) : ch;
    m1 = umax(m1, pv);
  }
#pragma unroll
  for (int m = 1; m < 64; m <<= 1) {
    uint32 o1 = (uint32)__shfl_xor((int)m1, m);
    uint32 o2 = (uint32)__shfl_xor((int)m2, m);
    int oc = __shfl_xor(ch, m);
    m2 = umax(umax(m2, o2), umin(m1, o1));
    ch = (o1 > m1) ? oc : ch;
    m1 = umax(m1, o1);
  }
  // all wave-uniform now
  float s1 = __uint_as_float(m1 & ~31u);
  float s2 = __uint_as_float(m2 & ~31u);
  int idx;
  if ((m1 & 16u) && (s1 - s2 > SM)) {
    idx = ch * 16 + (int)(m1 & 15u);  // provably the exact argmin
  } else {
    const float* zrow = flatz + (size_t)row * 256;
    unsigned long long key = chunk_exact(ch, zrow, cb, enorm, lane);
    float dbest;
    { unsigned int u = (unsigned int)(key >> 32);
      u = (u & 0x80000000u) ? (u & 0x7FFFFFFFu) : ~u;
      dbest = __uint_as_float(u); }
    float thr = (1024.f - 0.5f * dbest) - EPS_S;  // window lower bound
#pragma unroll
    for (int s = 0; s < 8; ++s) {
      bool cand = __uint_as_float(v[s] & ~31u) >= thr;
      unsigned long long mk = __ballot(cand);
      while (mk) {
        int L = __ffsll(mk) - 1;
        mk &= mk - 1;
        int c2 = L * 8 + s;
        if (c2 == ch) continue;
        key = u64min(key, chunk_exact(c2, zrow, cb, enorm, lane));
      }
    }
    idx = (int)(key & 0xFFFFFFFFull);
  }
  if (lane == 0) oidx[row] = (float)idx;
  float4 val = *(const float4*)(cb + (size_t)idx * 256 + lane * 4);
  *(float4*)(zq + (size_t)row * 256 + lane * 4) = val;  // exact fp32 gather
}

// ---- launch ----------------------------------------------------------------
extern "C" void kernel_launch(void* const* d_in, const int* in_sizes, int n_in,
                              void* d_out, int out_size, void* d_ws, size_t ws_size,
                              hipStream_t stream) {
  const float* z = (const float*)d_in[0];   // (16,256,32,32) fp32
  const float* cb = (const float*)d_in[1];  // (8192,256) fp32
  char* ws = (char*)d_ws;
  // ws: zb 8M@0 | eb 4M@8M | enorm 32K@12M | bm 32M@13M  (45 MB, proven fit)
  ushort* zb = (ushort*)(ws);
  ushort* eb = (ushort*)(ws + (8u << 20));
  float* enorm = (float*)(ws + (12u << 20));
  uint32* bm = (uint32*)(ws + (13u << 20));
  float* zq = (float*)d_out;               // (16384,256) fp32
  float* oidx = zq + (size_t)NROWS * DIM;  // (16384,) as fp32 values
  float* flatz = zq;  // NHWC fp32 z lives in zq until vq_sel overwrites per-row

  prep_z<<<dim3(32, 8, 16), 256, 0, stream>>>(z, flatz, zb);
  prep_cb<<<NCODES / 4, 256, 0, stream>>>(cb, eb, enorm);
  vq_gemm<<<dim3(NCODES / 128, NROWS / 256), 256, 0, stream>>>(eb, zb, enorm, bm);
  vq_sel<<<NROWS / 4, 256, 0, stream>>>(bm, flatz, cb, enorm, zq, oidx);
}

// Round 5
// 207.321 us; speedup vs baseline: 2.1945x; 1.2290x over previous
//
#include <hip/hip_runtime.h>
#include <stdint.h>

#define NROWS 16384   // 16*32*32 spatial positions
#define NCODES 8192
#define DIM 256
// score = 1024 + dot - ||e||^2/2  (higher = closer). bf16 dist-error sigma
// ~0.1 => score sigma ~0.05. EPS_S = 0.4 (8 sigma, one-sided); SM = 0.8.
// Dist-space equivalents 0.8 / 1.6. Validated absmax=0 in R4.
#define EPS_S 0.4f
#define SM 0.8f

typedef __attribute__((ext_vector_type(8))) short bf16x8;  // 8 bf16 = 4 VGPRs
typedef __attribute__((ext_vector_type(4))) float f32x4;
typedef unsigned int uint32;

__device__ __forceinline__ unsigned short f2bf(float f) {
  union { float f; unsigned int u; } v; v.f = f;
  unsigned int u = v.u;
  return (unsigned short)((u + 0x7FFFu + ((u >> 16) & 1u)) >> 16);  // RNE
}

__device__ __forceinline__ void glds16(const void* g, void* l) {
  __builtin_amdgcn_global_load_lds(
      (const __attribute__((address_space(1))) unsigned int*)g,
      (__attribute__((address_space(3))) unsigned int*)l, 16, 0, 0);
}

// exact-path u64 key = order-preserving dist bits << 32 | idx (min = best+lowest idx)
__device__ __forceinline__ unsigned long long packdi(float d, int idx) {
  unsigned int u = __float_as_uint(d);
  u = (u & 0x80000000u) ? ~u : (u | 0x80000000u);
  return ((unsigned long long)u << 32) | (unsigned int)idx;
}
__device__ __forceinline__ unsigned long long u64min(unsigned long long a,
                                                     unsigned long long b) {
  return a < b ? a : b;
}
__device__ __forceinline__ unsigned long long shflx64(unsigned long long v, int m) {
  int lo = __shfl_xor((int)(unsigned int)v, m);
  int hi = __shfl_xor((int)(v >> 32), m);
  return ((unsigned long long)(unsigned int)hi << 32) | (unsigned int)lo;
}
__device__ __forceinline__ uint32 umax(uint32 a, uint32 b) { return a > b ? a : b; }
__device__ __forceinline__ uint32 umin(uint32 a, uint32 b) { return a < b ? a : b; }

// ---- Phase 0a: NCHW -> (row, d) transpose; fp32 copy lives in zq (d_out) ---
__global__ __launch_bounds__(256) void prep_z(const float* __restrict__ z,
                                              float* __restrict__ flatz,
                                              ushort* __restrict__ zb) {
  __shared__ float t[32][33];
  const int tx = threadIdx.x & 31, ty = threadIdx.x >> 5;  // 32 x 8
  const int b = blockIdx.z, ct = blockIdx.y, ht = blockIdx.x;
  const float* src = z + (size_t)b * 262144 + (size_t)(ct * 32) * 1024 + ht * 32;
#pragma unroll
  for (int i = 0; i < 4; ++i) {
    int c = ty + i * 8;
    t[c][tx] = src[c * 1024 + tx];
  }
  __syncthreads();
#pragma unroll
  for (int i = 0; i < 4; ++i) {
    int hw = ty + i * 8;
    int row = b * 1024 + ht * 32 + hw;
    float v = t[tx][hw];
    flatz[(size_t)row * 256 + ct * 32 + tx] = v;
    zb[(size_t)row * 256 + ct * 32 + tx] = f2bf(v);
  }
}

// ---- Phase 0b: codebook -> bf16 + fp32 ||e||^2 -----------------------------
__global__ __launch_bounds__(256) void prep_cb(const float* __restrict__ cb,
                                               ushort* __restrict__ eb,
                                               float* __restrict__ enorm) {
  const int lane = threadIdx.x & 63, wave = threadIdx.x >> 6;
  const int code = blockIdx.x * 4 + wave;
  float4 v = *(const float4*)(cb + (size_t)code * 256 + lane * 4);
  ushort4 o;
  o.x = f2bf(v.x); o.y = f2bf(v.y); o.z = f2bf(v.z); o.w = f2bf(v.w);
  *(ushort4*)(eb + (size_t)code * 256 + lane * 4) = o;
  float ss = v.x * v.x + v.y * v.y + v.z * v.z + v.w * v.w;
#pragma unroll
  for (int s = 1; s < 64; s <<= 1) ss += __shfl_xor(ss, s);
  if (lane == 0) enorm[code] = ss;
}

// ---- Phase 1: bf16 MFMA score GEMM, A+B LDS dbuf (R3 skeleton) -------------
// 128 codes x 128 zrows, 4 waves = 2x2 quadrants of 64x64 (4i x 4j frags).
// Conflict-free swizzle: k-chunk (l&3)^((r>>1)&3) at slot l&3 of row r makes
// each 16-lane b128 group hit all 8 bank-quads exactly twice (2-way = free).
// Epilogue: per 16-code chunk store packed u32: score&~31 | gap-flag<<4 | id.
__global__ __launch_bounds__(256) void vq_gemm(const ushort* __restrict__ eb,
                                               const ushort* __restrict__ zb,
                                               const float* __restrict__ enorm,
                                               uint32* __restrict__ bm) {
  __shared__ __align__(16) ushort As[2][4096];  // 2 x (128 codes x 32 k) = 16 KB
  __shared__ __align__(16) ushort Bs[2][4096];  // 2 x (128 zrows x 32 k)
  const int tid = threadIdx.x;
  const int wave = tid >> 6, lane = tid & 63;
  const int wr = wave >> 1, wc = wave & 1;  // code half / zrow half
  const int code0 = blockIdx.x * 128;
  const int zrow0 = blockIdx.y * 128;
  const int q = lane >> 4, l15 = lane & 15;
  const int slot = (q ^ ((l15 >> 1) & 3)) * 8;  // conflict-free un-swizzle

  // acc init: 1024 - 0.5*||e||^2 (score trick) replicated across 4 j-frags
  f32x4 acc[4][4];
#pragma unroll
  for (int i = 0; i < 4; ++i) {
    float4 e = *(const float4*)(enorm + code0 + wr * 64 + i * 16 + q * 4);
    f32x4 c0 = {1024.f - 0.5f * e.x, 1024.f - 0.5f * e.y,
                1024.f - 0.5f * e.z, 1024.f - 0.5f * e.w};
#pragma unroll
    for (int j = 0; j < 4; ++j) acc[i][j] = c0;
  }

  // staging: lane l writes 16B to LDS slot l&3 of row l>>2 (glds constraint);
  // global k-chunk = (l&3) ^ ((l>>3)&3)  [= slot ^ g(row), g(r)=(r>>1)&3]
  const int r_in = lane >> 2;
  const int kc = (lane & 3) ^ ((lane >> 3) & 3);
  const ushort* aG0 = eb + (size_t)(code0 + wave * 16 + r_in) * 256 + kc * 8;
  const ushort* aG1 = eb + (size_t)(code0 + 64 + wave * 16 + r_in) * 256 + kc * 8;
  const ushort* bG0 = zb + (size_t)(zrow0 + wave * 16 + r_in) * 256 + kc * 8;
  const ushort* bG1 = zb + (size_t)(zrow0 + 64 + wave * 16 + r_in) * 256 + kc * 8;

  glds16(aG0, &As[0][wave * 512]);
  glds16(aG1, &As[0][(wave + 4) * 512]);
  glds16(bG0, &Bs[0][wave * 512]);
  glds16(bG1, &Bs[0][(wave + 4) * 512]);

#pragma unroll
  for (int k0 = 0; k0 < 8; ++k0) {
    const int cur = k0 & 1;
    __syncthreads();  // drains glds of stage k0; protects buf cur^1 reads
    if (k0 < 7) {
      glds16(aG0 + (k0 + 1) * 32, &As[cur ^ 1][wave * 512]);
      glds16(aG1 + (k0 + 1) * 32, &As[cur ^ 1][(wave + 4) * 512]);
      glds16(bG0 + (k0 + 1) * 32, &Bs[cur ^ 1][wave * 512]);
      glds16(bG1 + (k0 + 1) * 32, &Bs[cur ^ 1][(wave + 4) * 512]);
    }
    bf16x8 af[4], bf[4];
#pragma unroll
    for (int i = 0; i < 4; ++i)
      af[i] = *(const bf16x8*)(&As[cur][(wr * 64 + i * 16 + l15) * 32 + slot]);
#pragma unroll
    for (int j = 0; j < 4; ++j)
      bf[j] = *(const bf16x8*)(&Bs[cur][(wc * 64 + j * 16 + l15) * 32 + slot]);
#pragma unroll
    for (int i = 0; i < 4; ++i)
#pragma unroll
      for (int j = 0; j < 4; ++j)
        acc[i][j] = __builtin_amdgcn_mfma_f32_16x16x32_bf16(af[i], bf[j],
                                                            acc[i][j], 0, 0, 0);
  }

  // epilogue: C/D col=lane&15 (zrow), row=q*4+r (code-in-chunk). Pack id low
  // 4 bits (tie ids collide -> demoted to exact path), top-2 chains, flag
  // bit 4 = in-chunk gap > SM. One chunk16 per i-frag.
  const int cid0 = blockIdx.x * 8 + wr * 4;
#pragma unroll
  for (int j = 0; j < 4; ++j) {
    uint32 res[4];
#pragma unroll
    for (int i = 0; i < 4; ++i) {
      uint32 pv0 = (__float_as_uint(acc[i][j][0]) & ~31u) | (uint32)(q * 4 + 0);
      uint32 pv1 = (__float_as_uint(acc[i][j][1]) & ~31u) | (uint32)(q * 4 + 1);
      uint32 pv2 = (__float_as_uint(acc[i][j][2]) & ~31u) | (uint32)(q * 4 + 2);
      uint32 pv3 = (__float_as_uint(acc[i][j][3]) & ~31u) | (uint32)(q * 4 + 3);
      uint32 x01 = umax(pv0, pv1), n01 = umin(pv0, pv1);
      uint32 x23 = umax(pv2, pv3), n23 = umin(pv2, pv3);
      uint32 m1 = umax(x01, x23);
      uint32 m2 = umax(umin(x01, x23), umax(n01, n23));
#pragma unroll
      for (int m = 16; m < 64; m <<= 1) {  // merge the 4 q-groups
        uint32 o1 = (uint32)__shfl_xor((int)m1, m);
        uint32 o2 = (uint32)__shfl_xor((int)m2, m);
        m2 = umax(umax(m2, o2), umin(m1, o1));
        m1 = umax(m1, o1);
      }
      float s1 = __uint_as_float(m1 & ~31u);
      float s2 = __uint_as_float(m2 & ~31u);
      res[i] = (s1 - s2 > SM) ? (m1 | 16u) : m1;
    }
    if (lane < 16) {
      int zr = zrow0 + wc * 64 + j * 16 + l15;
      uint4 o; o.x = res[0]; o.y = res[1]; o.z = res[2]; o.w = res[3];
      *(uint4*)(bm + (size_t)zr * 512 + cid0) = o;
    }
  }
}

// exact fp32 distances for one 16-code chunk; summation order / lane split /
// tie-break bit-identical to the R2/R3/R4-validated slow path.
__device__ __forceinline__ unsigned long long chunk_exact(
    int chunk, const float* __restrict__ zrow, const float* __restrict__ cb,
    const float* __restrict__ enorm, int lane) {
  const int code = chunk * 16 + (lane >> 2);
  const float* zp = zrow + (lane & 3) * 64;
  const float* cp = cb + (size_t)code * 256 + (lane & 3) * 64;
  float s = 0.f;
#pragma unroll
  for (int d = 0; d < 64; d += 4) {
    float4 zv = *(const float4*)(zp + d);
    float4 cv = *(const float4*)(cp + d);
    s = fmaf(zv.x, cv.x, s); s = fmaf(zv.y, cv.y, s);
    s = fmaf(zv.z, cv.z, s); s = fmaf(zv.w, cv.w, s);
  }
  s += __shfl_xor(s, 1);
  s += __shfl_xor(s, 2);
  float dist = fmaf(-2.f, s, enorm[code]);
  unsigned long long key = ((lane & 3) == 0) ? packdi(dist, code) : ~0ull;
#pragma unroll
  for (int m = 1; m < 64; m <<= 1) key = u64min(key, shflx64(key, m));
  return key;  // wave-uniform
}

// ---- Phase 2: one wave per row (unchanged from R4, absmax-0 validated) -----
__global__ __launch_bounds__(256) void vq_sel(const uint32* __restrict__ bm,
                                              const float* __restrict__ flatz,
                                              const float* __restrict__ cb,
                                              const float* __restrict__ enorm,
                                              float* __restrict__ zq,
                                              float* __restrict__ oidx) {
  const int lane = threadIdx.x & 63;
  const int row = blockIdx.x * 4 + (threadIdx.x >> 6);
  uint4 va = *(const uint4*)(bm + (size_t)row * 512 + lane * 8);
  uint4 vb = *(const uint4*)(bm + (size_t)row * 512 + lane * 8 + 4);
  uint32 v[8] = {va.x, va.y, va.z, va.w, vb.x, vb.y, vb.z, vb.w};
  uint32 m1 = 0, m2 = 0; int ch = 0;
#pragma unroll
  for (int s = 0; s < 8; ++s) {
    uint32 pv = v[s];
    m2 = umax(m2, umin(m1, pv));
    ch = (pv > m1) ? (lane * 8 + s) : ch;
    m1 = umax(m1, pv);
  }
#pragma unroll
  for (int m = 1; m < 64; m <<= 1) {
    uint32 o1 = (uint32)__shfl_xor((int)m1, m);
    uint32 o2 = (uint32)__shfl_xor((int)m2, m);
    int oc = __shfl_xor(ch, m);
    m2 = umax(umax(m2, o2), umin(m1, o1));
    ch = (o1 > m1) ? oc : ch;
    m1 = umax(m1, o1);
  }
  // all wave-uniform now
  float s1 = __uint_as_float(m1 & ~31u);
  float s2 = __uint_as_float(m2 & ~31u);
  int idx;
  if ((m1 & 16u) && (s1 - s2 > SM)) {
    idx = ch * 16 + (int)(m1 & 15u);  // provably the exact argmin
  } else {
    const float* zrow = flatz + (size_t)row * 256;
    unsigned long long key = chunk_exact(ch, zrow, cb, enorm, lane);
    float dbest;
    { unsigned int u = (unsigned int)(key >> 32);
      u = (u & 0x80000000u) ? (u & 0x7FFFFFFFu) : ~u;
      dbest = __uint_as_float(u); }
    float thr = (1024.f - 0.5f * dbest) - EPS_S;  // window lower bound
#pragma unroll
    for (int s = 0; s < 8; ++s) {
      bool cand = __uint_as_float(v[s] & ~31u) >= thr;
      unsigned long long mk = __ballot(cand);
      while (mk) {
        int L = __ffsll(mk) - 1;
        mk &= mk - 1;
        int c2 = L * 8 + s;
        if (c2 == ch) continue;
        key = u64min(key, chunk_exact(c2, zrow, cb, enorm, lane));
      }
    }
    idx = (int)(key & 0xFFFFFFFFull);
  }
  if (lane == 0) oidx[row] = (float)idx;
  float4 val = *(const float4*)(cb + (size_t)idx * 256 + lane * 4);
  *(float4*)(zq + (size_t)row * 256 + lane * 4) = val;  // exact fp32 gather
}

// ---- launch ----------------------------------------------------------------
extern "C" void kernel_launch(void* const* d_in, const int* in_sizes, int n_in,
                              void* d_out, int out_size, void* d_ws, size_t ws_size,
                              hipStream_t stream) {
  const float* z = (const float*)d_in[0];   // (16,256,32,32) fp32
  const float* cb = (const float*)d_in[1];  // (8192,256) fp32
  char* ws = (char*)d_ws;
  // ws: zb 8M@0 | eb 4M@8M | enorm 32K@12M | bm 32M@13M  (45 MB, proven fit)
  ushort* zb = (ushort*)(ws);
  ushort* eb = (ushort*)(ws + (8u << 20));
  float* enorm = (float*)(ws + (12u << 20));
  uint32* bm = (uint32*)(ws + (13u << 20));
  float* zq = (float*)d_out;               // (16384,256) fp32
  float* oidx = zq + (size_t)NROWS * DIM;  // (16384,) as fp32 values
  float* flatz = zq;  // NHWC fp32 z lives in zq until vq_sel overwrites per-row

  prep_z<<<dim3(32, 8, 16), 256, 0, stream>>>(z, flatz, zb);
  prep_cb<<<NCODES / 4, 256, 0, stream>>>(cb, eb, enorm);
  vq_gemm<<<dim3(NCODES / 128, NROWS / 128), 256, 0, stream>>>(eb, zb, enorm, bm);
  vq_sel<<<NROWS / 4, 256, 0, stream>>>(bm, flatz, cb, enorm, zq, oidx);
}